// Round 5
// baseline (203.635 us; speedup 1.0000x reference)
//
#include <hip/hip_runtime.h>
#include <stdint.h>

#define N 8192
#define C 512
#define BM 128
#define BN 128
#define BKF 128                       /* fp8 bytes per K-tile */
#define NSPLIT 16
#define COLS_PER_SPLIT (N / NSPLIT)   /* 512 */
#define CT (COLS_PER_SPLIT / BN)      /* 4 */
#define GRID_GEMM (64 * NSPLIT)       /* 1024 */
#define INV_T 14.285714285714286f

typedef __attribute__((ext_vector_type(4)))  int   i32x4;
typedef __attribute__((ext_vector_type(8)))  int   i32x8;
typedef __attribute__((ext_vector_type(16))) float f32x16;

// ---- fused prep: fp32 -> fp8 e4m3 (HW cvt) for X and Y + exact fp32 pos ----
// one wave per row (C=512 floats, 8/lane); block 0 also zeroes the ticket
__global__ __launch_bounds__(256) void prep_kernel(const float* __restrict__ X,
                                                   const float* __restrict__ Y,
                                                   unsigned char* __restrict__ Xf8,
                                                   unsigned char* __restrict__ Yf8,
                                                   float* __restrict__ pos,
                                                   unsigned* __restrict__ ticket) {
  if (blockIdx.x == 0 && threadIdx.x == 0) *ticket = 0u;
  const int wave = threadIdx.x >> 6;
  const int lane = threadIdx.x & 63;
  const int row = blockIdx.x * 4 + wave;
  const float4* xr = (const float4*)(X + (size_t)row * C) + lane * 2;
  const float4* yr = (const float4*)(Y + (size_t)row * C) + lane * 2;
  float4 x0 = xr[0], x1 = xr[1];
  float4 y0 = yr[0], y1 = yr[1];
  float s = x0.x * y0.x + x0.y * y0.y + x0.z * y0.z + x0.w * y0.w
          + x1.x * y1.x + x1.y * y1.y + x1.z * y1.z + x1.w * y1.w;
  int2 ox, oy;
  ox.x = __builtin_amdgcn_cvt_pk_fp8_f32(x0.x, x0.y, 0, false);
  ox.x = __builtin_amdgcn_cvt_pk_fp8_f32(x0.z, x0.w, ox.x, true);
  ox.y = __builtin_amdgcn_cvt_pk_fp8_f32(x1.x, x1.y, 0, false);
  ox.y = __builtin_amdgcn_cvt_pk_fp8_f32(x1.z, x1.w, ox.y, true);
  oy.x = __builtin_amdgcn_cvt_pk_fp8_f32(y0.x, y0.y, 0, false);
  oy.x = __builtin_amdgcn_cvt_pk_fp8_f32(y0.z, y0.w, oy.x, true);
  oy.y = __builtin_amdgcn_cvt_pk_fp8_f32(y1.x, y1.y, 0, false);
  oy.y = __builtin_amdgcn_cvt_pk_fp8_f32(y1.z, y1.w, oy.y, true);
  ((int2*)(Xf8 + (size_t)row * C))[lane] = ox;
  ((int2*)(Yf8 + (size_t)row * C))[lane] = oy;
#pragma unroll
  for (int off = 32; off >= 1; off >>= 1) s += __shfl_xor(s, off);
  if (lane == 0) pos[row] = s * INV_T;
}

// ---- main: 128x128-tile MX-scaled fp8 MFMA (scale=1.0) + online lse ----
// + fused last-block combine via device-scope ticket.
// Wave w owns rows [w*32, +32) x 128 cols: 4x 32x32x64 f8f6f4 accs.
// LDS XOR-swizzle: logical 16B chunk j of row r at physical chunk j^(r&7).
__global__ __launch_bounds__(256, 3) void gemm_lse_kernel(const unsigned char* __restrict__ Xf8,
                                                          const unsigned char* __restrict__ Yf8,
                                                          float2* __restrict__ partials,
                                                          const float* __restrict__ pos,
                                                          unsigned* __restrict__ ticket,
                                                          float* __restrict__ out) {
  __shared__ unsigned char As[BM][BKF];   // 16 KB (physical, swizzled)
  __shared__ unsigned char Bs[BN][BKF];   // 16 KB

  const int tid = threadIdx.x;
  const int bx = blockIdx.x;
  const int split = bx & (NSPLIT - 1);
  const int rb = bx >> 4;                 // 0..63
  const int row0 = rb * BM;
  const int colbase = split * COLS_PER_SPLIT;

  const int w = tid >> 6;                 // wave 0..3: rows [w*32, +32)
  const int lane = tid & 63;
  const int lrow = lane & 31;
  const int h = lane >> 5;                // k-half selector
  const int arow = w * 32 + lrow;
  const int swz = lrow & 7;

  float m_s[16], l_s[16];
#pragma unroll
  for (int s = 0; s < 16; ++s) { m_s[s] = -INFINITY; l_s[s] = 0.0f; }

  const int r_base = tid >> 3;
  const int p = tid & 7;
  const int j = p ^ (r_base & 7);

  for (int ct = 0; ct < CT; ++ct) {
    const int col0 = colbase + ct * BN;
    f32x16 acc[4];
#pragma unroll
    for (int t = 0; t < 4; ++t)
#pragma unroll
      for (int e = 0; e < 16; ++e) acc[t][e] = 0.0f;

    for (int k0 = 0; k0 < C; k0 += BKF) {
#pragma unroll
      for (int i = 0; i < 4; ++i) {
        const int r = i * 32 + r_base;
        const unsigned char* ga = Xf8 + (size_t)(row0 + r) * C + (k0 + j * 16);
        const unsigned char* gb = Yf8 + (size_t)(col0 + r) * C + (k0 + j * 16);
        uint32_t loff = (uint32_t)((i * 256 + (tid & ~63)) * 16);
        __builtin_amdgcn_global_load_lds(
            (const __attribute__((address_space(1))) uint32_t*)(uintptr_t)ga,
            (__attribute__((address_space(3))) uint32_t*)(uintptr_t)((char*)&As[0][0] + loff),
            16, 0, 0);
        __builtin_amdgcn_global_load_lds(
            (const __attribute__((address_space(1))) uint32_t*)(uintptr_t)gb,
            (__attribute__((address_space(3))) uint32_t*)(uintptr_t)((char*)&Bs[0][0] + loff),
            16, 0, 0);
      }
      __syncthreads();
#pragma unroll
      for (int s = 0; s < 2; ++s) {
        const int c0 = 4 * s + 2 * h;
        i32x4 alo = *(const i32x4*)&As[arow][((c0    ) ^ swz) * 16];
        i32x4 ahi = *(const i32x4*)&As[arow][((c0 + 1) ^ swz) * 16];
        i32x8 af = { alo[0], alo[1], alo[2], alo[3], ahi[0], ahi[1], ahi[2], ahi[3] };
#pragma unroll
        for (int tj = 0; tj < 4; ++tj) {
          const int brow = tj * 32 + lrow;
          i32x4 blo = *(const i32x4*)&Bs[brow][((c0    ) ^ swz) * 16];
          i32x4 bhi = *(const i32x4*)&Bs[brow][((c0 + 1) ^ swz) * 16];
          i32x8 bf = { blo[0], blo[1], blo[2], blo[3], bhi[0], bhi[1], bhi[2], bhi[3] };
          acc[tj] = __builtin_amdgcn_mfma_scale_f32_32x32x64_f8f6f4(
              af, bf, acc[tj], 0, 0, 0, 127, 0, 127);
        }
      }
      __syncthreads();
    }

#pragma unroll
    for (int r = 0; r < 16; ++r) {
      float v0 = acc[0][r] * INV_T;
      float v1 = acc[1][r] * INV_T;
      float v2 = acc[2][r] * INV_T;
      float v3 = acc[3][r] * INV_T;
      float mx = fmaxf(fmaxf(v0, v1), fmaxf(v2, v3));
      float mn = fmaxf(m_s[r], mx);
      l_s[r] = l_s[r] * __expf(m_s[r] - mn)
             + __expf(v0 - mn) + __expf(v1 - mn) + __expf(v2 - mn) + __expf(v3 - mn);
      m_s[r] = mn;
    }
  }

  // merge across the 32 lanes (cols) sharing each row-set
#pragma unroll
  for (int r = 0; r < 16; ++r) {
    float m = m_s[r], l = l_s[r];
#pragma unroll
    for (int off = 1; off < 32; off <<= 1) {
      float mo = __shfl_xor(m, off);
      float lo = __shfl_xor(l, off);
      float mn = fmaxf(m, mo);
      l = l * __expf(m - mn) + lo * __expf(mo - mn);
      m = mn;
    }
    m_s[r] = m; l_s[r] = l;
  }
  // partials are SPLIT-MAJOR: partials[split*N + row] (coalesced combine reads)
  if (lrow == 0) {
#pragma unroll
    for (int r = 0; r < 16; ++r) {
      int row_local = (r & 3) + 8 * (r >> 2) + 4 * h;
      partials[(size_t)split * N + (row0 + w * 32 + row_local)] =
          make_float2(m_s[r], l_s[r]);
    }
  }

  // ---- ticket: last block to finish performs the combine ----
  __syncthreads();                        // all partial stores issued & drained
  __shared__ unsigned last;
  if (tid == 0) {
    __threadfence();                      // device-scope release of this XCD's writes
    unsigned rank = __hip_atomic_fetch_add(ticket, 1u, __ATOMIC_ACQ_REL,
                                           __HIP_MEMORY_SCOPE_AGENT);
    last = (rank == GRID_GEMM - 1) ? 1u : 0u;
  }
  __syncthreads();
  if (last) {
    // combine: 256 threads, 32 rows each; split-major reads are coalesced
    float v = 0.0f;
    for (int k = 0; k < 32; ++k) {
      const int row = tid + 256 * k;
      float M = -INFINITY, L = 0.0f;
#pragma unroll
      for (int s = 0; s < NSPLIT; ++s) {
        float2 pr = partials[(size_t)s * N + row];
        float mn = fmaxf(M, pr.x);
        L = L * __expf(M - mn) + pr.y * __expf(pr.x - mn);
        M = mn;
      }
      v += M + __logf(L) - pos[row];
    }
#pragma unroll
    for (int off = 32; off >= 1; off >>= 1) v += __shfl_xor(v, off);
    __shared__ float wsum[4];
    if ((tid & 63) == 0) wsum[tid >> 6] = v;
    __syncthreads();
    if (tid == 0) out[0] = wsum[0] + wsum[1] + wsum[2] + wsum[3];
  }
}

extern "C" void kernel_launch(void* const* d_in, const int* in_sizes, int n_in,
                              void* d_out, int out_size, void* d_ws, size_t ws_size,
                              hipStream_t stream) {
  const float* X = (const float*)d_in[0];
  const float* Y = (const float*)d_in[1];
  float* out = (float*)d_out;

  // workspace: Xf8 (4MB) | Yf8 (4MB) | partials (1MB) | pos (32KB) | ticket
  char* w = (char*)d_ws;
  unsigned char* Xf8 = (unsigned char*)w;
  unsigned char* Yf8 = Xf8 + (size_t)N * C;
  float2* partials = (float2*)(Yf8 + (size_t)N * C);
  float* pos = (float*)((char*)partials + (size_t)NSPLIT * N * sizeof(float2));
  unsigned* ticket = (unsigned*)(pos + N);

  prep_kernel<<<N / 4, 256, 0, stream>>>(X, Y, Xf8, Yf8, pos, ticket);
  gemm_lse_kernel<<<GRID_GEMM, 256, 0, stream>>>(Xf8, Yf8, partials, pos, ticket, out);
}

// Round 6
// 123.180 us; speedup vs baseline: 1.6531x; 1.6531x over previous
//
#include <hip/hip_runtime.h>
#include <stdint.h>

#define N 8192
#define C 512
#define BM 128
#define BN 128
#define BKF 128                       /* fp8 bytes per K-tile */
#define NSPLIT 8
#define COLS_PER_SPLIT (N / NSPLIT)   /* 1024 */
#define CT (COLS_PER_SPLIT / BN)      /* 8 */
#define GRID_GEMM (64 * NSPLIT)       /* 512 = 2 blocks/CU, single round */
#define INV_T 14.285714285714286f

typedef __attribute__((ext_vector_type(4)))  int   i32x4;
typedef __attribute__((ext_vector_type(8)))  int   i32x8;
typedef __attribute__((ext_vector_type(16))) float f32x16;

// ---- fused prep: fp32 -> fp8 e4m3 (HW cvt) for X and Y + exact fp32 pos ----
__global__ __launch_bounds__(256) void prep_kernel(const float* __restrict__ X,
                                                   const float* __restrict__ Y,
                                                   unsigned char* __restrict__ Xf8,
                                                   unsigned char* __restrict__ Yf8,
                                                   float* __restrict__ pos) {
  const int wave = threadIdx.x >> 6;
  const int lane = threadIdx.x & 63;
  const int row = blockIdx.x * 4 + wave;
  const float4* xr = (const float4*)(X + (size_t)row * C) + lane * 2;
  const float4* yr = (const float4*)(Y + (size_t)row * C) + lane * 2;
  float4 x0 = xr[0], x1 = xr[1];
  float4 y0 = yr[0], y1 = yr[1];
  float s = x0.x * y0.x + x0.y * y0.y + x0.z * y0.z + x0.w * y0.w
          + x1.x * y1.x + x1.y * y1.y + x1.z * y1.z + x1.w * y1.w;
  int2 ox, oy;
  ox.x = __builtin_amdgcn_cvt_pk_fp8_f32(x0.x, x0.y, 0, false);
  ox.x = __builtin_amdgcn_cvt_pk_fp8_f32(x0.z, x0.w, ox.x, true);
  ox.y = __builtin_amdgcn_cvt_pk_fp8_f32(x1.x, x1.y, 0, false);
  ox.y = __builtin_amdgcn_cvt_pk_fp8_f32(x1.z, x1.w, ox.y, true);
  oy.x = __builtin_amdgcn_cvt_pk_fp8_f32(y0.x, y0.y, 0, false);
  oy.x = __builtin_amdgcn_cvt_pk_fp8_f32(y0.z, y0.w, oy.x, true);
  oy.y = __builtin_amdgcn_cvt_pk_fp8_f32(y1.x, y1.y, 0, false);
  oy.y = __builtin_amdgcn_cvt_pk_fp8_f32(y1.z, y1.w, oy.y, true);
  ((int2*)(Xf8 + (size_t)row * C))[lane] = ox;
  ((int2*)(Yf8 + (size_t)row * C))[lane] = oy;
#pragma unroll
  for (int off = 32; off >= 1; off >>= 1) s += __shfl_xor(s, off);
  if (lane == 0) pos[row] = s * INV_T;
}

// ---- main: MX-scaled fp8 MFMA (scale=1.0) + online lse ----
// A staged ONCE per block for full K (64 KB LDS); B restaged per (ct,k0).
// LDS XOR-swizzle within each 128B segment: logical 16B chunk j of row r at
// physical chunk j^(r&7). Wave w owns rows [w*32,+32) x 128 cols.
__global__ __launch_bounds__(256, 2) void gemm_lse_kernel(const unsigned char* __restrict__ Xf8,
                                                          const unsigned char* __restrict__ Yf8,
                                                          float2* __restrict__ partials) {
  __shared__ unsigned char As[BM][C];     // 64 KB full-K A tile (swizzled)
  __shared__ unsigned char Bs[BN][BKF];   // 16 KB B k-tile (swizzled)

  const int tid = threadIdx.x;
  const int bx = blockIdx.x;
  const int split = bx & (NSPLIT - 1);
  const int rb = bx >> 3;                 // 0..63
  const int row0 = rb * BM;
  const int colbase = split * COLS_PER_SPLIT;

  const int w = tid >> 6;                 // wave 0..3: rows [w*32, +32)
  const int lane = tid & 63;
  const int lrow = lane & 31;
  const int h = lane >> 5;                // k-half selector
  const int arow = w * 32 + lrow;
  const int swz = lrow & 7;

  // ---- stage full-K A tile once: 128 rows x 512 B = 4096 16B-chunks ----
#pragma unroll
  for (int t = 0; t < 16; ++t) {
    const int s2 = t * 256 + tid;         // physical chunk id 0..4095
    const int r = s2 >> 5;                // row (32 chunks/row)
    const int cir = s2 & 31;              // chunk within row
    const int k0t = cir >> 3;             // 128B segment
    const int p = cir & 7;                // physical chunk within segment
    const int jj = p ^ (r & 7);           // logical chunk to fetch
    const unsigned char* ga = Xf8 + (size_t)(row0 + r) * C + k0t * BKF + jj * 16;
    uint32_t loff = (uint32_t)((t * 256 + (tid & ~63)) * 16);
    __builtin_amdgcn_global_load_lds(
        (const __attribute__((address_space(1))) uint32_t*)(uintptr_t)ga,
        (__attribute__((address_space(3))) uint32_t*)(uintptr_t)((char*)&As[0][0] + loff),
        16, 0, 0);
  }

  float m_s[16], l_s[16];
#pragma unroll
  for (int s = 0; s < 16; ++s) { m_s[s] = -INFINITY; l_s[s] = 0.0f; }

  // B staging-lane invariants
  const int r_base = tid >> 3;            // row within 32-row group
  const int p = tid & 7;
  const int j = p ^ (r_base & 7);

  for (int ct = 0; ct < CT; ++ct) {
    const int col0 = colbase + ct * BN;
    f32x16 acc[4];
#pragma unroll
    for (int t = 0; t < 4; ++t)
#pragma unroll
      for (int e = 0; e < 16; ++e) acc[t][e] = 0.0f;

    for (int k0 = 0; k0 < C / BKF; ++k0) {
      // stage B[128][128B]: 1024 chunks, 4 instrs x 256 threads
#pragma unroll
      for (int i = 0; i < 4; ++i) {
        const int r = i * 32 + r_base;
        const unsigned char* gb = Yf8 + (size_t)(col0 + r) * C + k0 * BKF + j * 16;
        uint32_t loff = (uint32_t)((i * 256 + (tid & ~63)) * 16);
        __builtin_amdgcn_global_load_lds(
            (const __attribute__((address_space(1))) uint32_t*)(uintptr_t)gb,
            (__attribute__((address_space(3))) uint32_t*)(uintptr_t)((char*)&Bs[0][0] + loff),
            16, 0, 0);
      }
      __syncthreads();                    // drains B (and A on first iteration)
#pragma unroll
      for (int s = 0; s < 2; ++s) {       // two K=64 steps per 128B segment
        const int c0 = 4 * s + 2 * h;
        i32x4 alo = *(const i32x4*)&As[arow][k0 * BKF + (((c0    ) ^ swz) * 16)];
        i32x4 ahi = *(const i32x4*)&As[arow][k0 * BKF + (((c0 + 1) ^ swz) * 16)];
        i32x8 af = { alo[0], alo[1], alo[2], alo[3], ahi[0], ahi[1], ahi[2], ahi[3] };
#pragma unroll
        for (int tj = 0; tj < 4; ++tj) {
          const int brow = tj * 32 + lrow;
          i32x4 blo = *(const i32x4*)&Bs[brow][((c0    ) ^ swz) * 16];
          i32x4 bhi = *(const i32x4*)&Bs[brow][((c0 + 1) ^ swz) * 16];
          i32x8 bf = { blo[0], blo[1], blo[2], blo[3], bhi[0], bhi[1], bhi[2], bhi[3] };
          acc[tj] = __builtin_amdgcn_mfma_scale_f32_32x32x64_f8f6f4(
              af, bf, acc[tj], 0, 0, 0, 127, 0, 127);
        }
      }
      __syncthreads();
    }

    // per-lane online update over this 128-col tile
#pragma unroll
    for (int r = 0; r < 16; ++r) {
      float v0 = acc[0][r] * INV_T;
      float v1 = acc[1][r] * INV_T;
      float v2 = acc[2][r] * INV_T;
      float v3 = acc[3][r] * INV_T;
      float mx = fmaxf(fmaxf(v0, v1), fmaxf(v2, v3));
      float mn = fmaxf(m_s[r], mx);
      l_s[r] = l_s[r] * __expf(m_s[r] - mn)
             + __expf(v0 - mn) + __expf(v1 - mn) + __expf(v2 - mn) + __expf(v3 - mn);
      m_s[r] = mn;
    }
  }

  // merge across the 32 lanes (cols) sharing each row-set
#pragma unroll
  for (int r = 0; r < 16; ++r) {
    float m = m_s[r], l = l_s[r];
#pragma unroll
    for (int off = 1; off < 32; off <<= 1) {
      float mo = __shfl_xor(m, off);
      float lo = __shfl_xor(l, off);
      float mn = fmaxf(m, mo);
      l = l * __expf(m - mn) + lo * __expf(mo - mn);
      m = mn;
    }
    m_s[r] = m; l_s[r] = l;
  }
  // split-major partials: partials[split*N + row] (coalesced combine reads)
  if (lrow == 0) {
#pragma unroll
    for (int r = 0; r < 16; ++r) {
      int row_local = (r & 3) + 8 * (r >> 2) + 4 * h;
      partials[(size_t)split * N + (row0 + w * 32 + row_local)] =
          make_float2(m_s[r], l_s[r]);
    }
  }
}

// ---- combine: per-row merge of NSPLIT partials, subtract pos, global sum ----
__global__ __launch_bounds__(256) void combine_kernel(const float2* __restrict__ partials,
                                                      const float* __restrict__ pos,
                                                      float* __restrict__ out) {
  int row = blockIdx.x * 256 + threadIdx.x;
  float M = -INFINITY, L = 0.0f;
#pragma unroll
  for (int s = 0; s < NSPLIT; ++s) {
    float2 pr = partials[(size_t)s * N + row];
    float mn = fmaxf(M, pr.x);
    L = L * __expf(M - mn) + pr.y * __expf(pr.x - mn);
    M = mn;
  }
  float v = M + __logf(L) - pos[row];
#pragma unroll
  for (int off = 32; off >= 1; off >>= 1) v += __shfl_xor(v, off);
  __shared__ float wsum[4];
  if ((threadIdx.x & 63) == 0) wsum[threadIdx.x >> 6] = v;
  __syncthreads();
  if (threadIdx.x == 0) atomicAdd(out, wsum[0] + wsum[1] + wsum[2] + wsum[3]);
}

extern "C" void kernel_launch(void* const* d_in, const int* in_sizes, int n_in,
                              void* d_out, int out_size, void* d_ws, size_t ws_size,
                              hipStream_t stream) {
  const float* X = (const float*)d_in[0];
  const float* Y = (const float*)d_in[1];
  float* out = (float*)d_out;

  // workspace: Xf8 (4MB) | Yf8 (4MB) | partials (512KB) | pos (32KB)
  char* w = (char*)d_ws;
  unsigned char* Xf8 = (unsigned char*)w;
  unsigned char* Yf8 = Xf8 + (size_t)N * C;
  float2* partials = (float2*)(Yf8 + (size_t)N * C);
  float* pos = (float*)((char*)partials + (size_t)NSPLIT * N * sizeof(float2));

  hipMemsetAsync(d_out, 0, sizeof(float), stream);
  prep_kernel<<<N / 4, 256, 0, stream>>>(X, Y, Xf8, Yf8, pos);
  gemm_lse_kernel<<<GRID_GEMM, 256, 0, stream>>>(Xf8, Yf8, partials);
  combine_kernel<<<N / 256, 256, 0, stream>>>(partials, pos, out);
}